// Round 3
// baseline (105.240 us; speedup 1.0000x reference)
//
#include <hip/hip_runtime.h>
#include <hip/hip_bf16.h>

// GAT layer: B=8, N=2048, Fin=256, Fout=128  (f32 in / f32 out)
// Wh = h@W ; s1 = Wh@a1 ; s2 = Wh@a2
// P[i,j] = softmax_i( lrelu(s1_i+s2_j) ) ; out = elu(P @ Wh)
// R16: 3 kernels (was 4). Evidence: 3 structurally different k_pv all land
//      within +-3%, arithmetic floor of kernels ~13us << 104us measured ->
//      fixed cost (268MB poison fill ~44us + per-node gaps) dominates.
//      (1) k_prep deleted: k_wh converts W inline (L1-resident 16KB/kt slice,
//          identical bf16 rounding). (2) k_wh writes WhT directly from acc
//          (no tt LDS, one less barrier, 8B dwordx2 stores, 256B segments).
//      (3) k_pv = R14 DMA-dbuf (best measured) + R15 A/B fusion (no s2/lz
//          staging, exponent = max(s1a+A, a*s1a+B)).

#define ALPHA 0.2f
#define LOG2E 1.4426950408889634f
constexpr int Bb=8, Nn=2048, FIN=256, FOUT=128;

typedef __attribute__((ext_vector_type(8))) short short8;
typedef __attribute__((ext_vector_type(4))) float f32x4;
typedef __attribute__((ext_vector_type(16))) float f32x16;
typedef const __attribute__((address_space(1))) unsigned int* gptr_t;
typedef __attribute__((address_space(3))) unsigned int* lptr_t;

__device__ __forceinline__ float lrelu(float x){ return fmaxf(x, ALPHA*x); }
__device__ __forceinline__ unsigned short bfbits(float x){
    __hip_bfloat16 h = __float2bfloat16(x);
    return *(unsigned short*)&h;
}

// ---- K1: Wh = h@W via MFMA -> s1,s2 (xLOG2E), WhT supertiles for k_pv ----
// h DMA-staged to LDS (row stride 260 f32, minimal-round banks). W converted
// inline from f32 (16KB per-kt slice stays L1-resident across waves/blocks).
__global__ __launch_bounds__(256) void k_wh(const float* __restrict__ h,
                                            const float* __restrict__ W,
                                            const float* __restrict__ a,
                                            float* __restrict__ s1,
                                            float* __restrict__ s2,
                                            __hip_bfloat16* __restrict__ WhT){
    const int blk = blockIdx.x;            // 512
    const int rowbase = blk * 32;
    const int b = blk >> 6;
    const int jt = (rowbase & (Nn-1)) >> 5;     // 64 32-row tiles per batch
    const int t = threadIdx.x;
    const int wave = t>>6, lane = t&63;
    const int wm = wave & 1, wn = wave >> 1;
    const int lm = lane & 15, q = lane >> 4;

    __shared__ __align__(16) float hs[32*260];      // 33.3 KB, stride 260
    __shared__ float s1red[2][32], s2red[2][32];

    {   // DMA h rows: wave w stages rows w*8..w*8+7 (1 KB per instr per row)
        const float* srcbase = h + (size_t)rowbase*FIN;
        #pragma unroll
        for (int c = 0; c < 8; ++c){
            const int row = wave*8 + c;
            __builtin_amdgcn_global_load_lds(
                (gptr_t)(srcbase + (size_t)row*FIN + lane*4),
                (lptr_t)&hs[row*260], 16, 0, 0);
        }
    }
    __syncthreads();   // drains DMA (compiler emits vmcnt(0) before barrier)

    f32x4 acc[4];
    #pragma unroll
    for (int ntl = 0; ntl < 4; ++ntl) acc[ntl] = (f32x4){0.f,0.f,0.f,0.f};

    const float* hrow = &hs[(wm*16 + lm)*260];
    const float* Wq   = W + (size_t)(q*8)*FOUT + wn*64 + lm;   // per-thread W base
    #pragma unroll
    for (int kt = 0; kt < 8; ++kt){
        float av[8];
        *(float4*)&av[0] = *(const float4*)&hrow[kt*32 + q*8];
        *(float4*)&av[4] = *(const float4*)&hrow[kt*32 + q*8 + 4];
        short8 afr;
        #pragma unroll
        for (int e = 0; e < 8; ++e) afr[e] = (short)bfbits(av[e]);
        const float* Wkt = Wq + (size_t)kt*32*FOUT;
        #pragma unroll
        for (int ntl = 0; ntl < 4; ++ntl){
            const float* Wp = Wkt + ntl*16;
            short8 bfr;
            #pragma unroll
            for (int e = 0; e < 8; ++e) bfr[e] = (short)bfbits(Wp[(size_t)e*FOUT]);
            acc[ntl] = __builtin_amdgcn_mfma_f32_16x16x32_bf16(afr, bfr, acc[ntl], 0,0,0);
        }
    }

    {   // s1/s2 partials over this wave's 64 cols, lm-reduce
        float a1v[4], a2v[4];
        #pragma unroll
        for (int ntl = 0; ntl < 4; ++ntl){
            a1v[ntl] = a[wn*64 + ntl*16 + lm];
            a2v[ntl] = a[FOUT + wn*64 + ntl*16 + lm];
        }
        #pragma unroll
        for (int rg = 0; rg < 4; ++rg){
            float p1 = 0.f, p2 = 0.f;
            #pragma unroll
            for (int ntl = 0; ntl < 4; ++ntl){
                p1 += acc[ntl][rg]*a1v[ntl];
                p2 += acc[ntl][rg]*a2v[ntl];
            }
            #pragma unroll
            for (int m = 1; m < 16; m <<= 1){
                p1 += __shfl_xor(p1, m);
                p2 += __shfl_xor(p2, m);
            }
            if (lm == 0){
                s1red[wn][wm*16 + q*4 + rg] = p1;
                s2red[wn][wm*16 + q*4 + rg] = p2;
            }
        }
    }

    {   // WhT supertile write DIRECT from acc. C layout (16x16x32, m89):
        // token jj = wm*16 + q*4 + rg, d = wn*64 + ntl*16 + lm.
        // unit u = (s*4+nt)*64 + l5*32 + col; s=(jt&1)*2+wm, l5=q>>1,
        // nt=d>>5, col=d&31, elem e=jj&7=(q&1)*4+rg -> ushort4 @ u*8+(q&1)*4.
        short* Wo = (short*)WhT;
        const size_t tb = ((size_t)(b*32 + (jt >> 1)))*8192;   // supertile base (shorts)
        const int s  = (jt & 1)*2 + wm;
        const int l5 = q >> 1, ehalf = (q & 1)*4;
        #pragma unroll
        for (int ntl = 0; ntl < 4; ++ntl){
            const int d = wn*64 + ntl*16 + lm;
            const int u = (s*4 + (d>>5))*64 + l5*32 + (d & 31);
            ushort4 v;
            v.x = bfbits(acc[ntl][0]); v.y = bfbits(acc[ntl][1]);
            v.z = bfbits(acc[ntl][2]); v.w = bfbits(acc[ntl][3]);
            *(ushort4*)&Wo[tb + (size_t)u*8 + ehalf] = v;
        }
    }

    __syncthreads();
    if (t < 32){
        s1[rowbase + t] = (s1red[0][t] + s1red[1][t]) * LOG2E;
        s2[rowbase + t] = (s2red[0][t] + s2red[1][t]) * LOG2E;
    }
}

// ---- K2: A[b,j] = s2j - log2(Zj), Bz[b,j] = ALPHA*s2j - log2(Zj) ----
// (s1,s2 pre-scaled by LOG2E; exponent in k_pv = max(s1a+A, a*s1a+Bz))
__global__ __launch_bounds__(256) void k_z(const float* __restrict__ s1,
                                           const float* __restrict__ s2,
                                           float* __restrict__ Aout,
                                           float* __restrict__ Bout){
    const int b  = blockIdx.x >> 6;      // 512 blocks, 32 j each
    const int jt = blockIdx.x & 63;
    const int t  = threadIdx.x;
    const int jj = t & 31, part = t >> 5;
    const int j  = jt*32 + jj;
    __shared__ float s1s[Nn];
    __shared__ float red[8][33];

    {
        const float4* g = (const float4*)(s1 + (size_t)b*Nn);
        float4* p = (float4*)s1s;
        #pragma unroll
        for (int v0 = 0; v0 < 2; ++v0){ const int v = t + v0*256; p[v] = g[v]; }
    }
    __syncthreads();
    const float s2j = s2[b*Nn + j];
    float sum = 0.f;
    const float4* s4 = (const float4*)&s1s[part*256];
    #pragma unroll 4
    for (int v = 0; v < 64; ++v){
        float x[4]; *(float4*)x = s4[v];
        sum += __builtin_amdgcn_exp2f(lrelu(x[0]+s2j))
             + __builtin_amdgcn_exp2f(lrelu(x[1]+s2j))
             + __builtin_amdgcn_exp2f(lrelu(x[2]+s2j))
             + __builtin_amdgcn_exp2f(lrelu(x[3]+s2j));
    }
    red[part][jj] = sum;
    __syncthreads();
    if (part == 0){
        float Z = 0.f;
        #pragma unroll
        for (int p = 0; p < 8; ++p) Z += red[p][jj];
        const float lz = -__builtin_amdgcn_logf(Z);   // v_log_f32 = log2
        Aout[b*Nn + j] = s2j + lz;
        Bout[b*Nn + j] = ALPHA*s2j + lz;
    }
}

// ---- K3: out = elu(P @ Wh), 32x32x16 MFMA, DMA double-buffer (R14) ----
// 256 blocks (1/CU), 8 waves = 2 row-groups x 4 j-quarters. Each quarter
// double-buffers its 16 KB supertile stream; A/B read direct from global.
__global__ __launch_bounds__(512, 2) void k_pv(const float* __restrict__ s1,
                                               const float* __restrict__ Aarr,
                                               const float* __restrict__ Barr,
                                               const __hip_bfloat16* __restrict__ WhT,
                                               float* __restrict__ out){
    const int blk   = blockIdx.x;          // 256 (b = blk&7 pins batch to XCD)
    const int b     = blk & 7;
    const int ibase = (blk >> 3) * 64;
    const int t     = threadIdx.x;
    const int wave  = t >> 6, lane = t & 63;
    const int wr = wave & 1, kh = wave >> 1;
    const int il = lane & 31, l5 = lane >> 5;

    __shared__ unsigned short Bs[2][4][8192];          // 128 KB: dbuf x quarter

    const float s1a  = s1[(size_t)b*Nn + ibase + wr*32 + il];
    const float as1a = ALPHA * s1a;
    const float* Ab = Aarr + (size_t)b*Nn;
    const float* Zb = Barr + (size_t)b*Nn;

    f32x16 acc[4];
    #pragma unroll
    for (int nt = 0; nt < 4; ++nt)
        #pragma unroll
        for (int e = 0; e < 16; ++e) acc[nt][e] = 0.f;

    const char* Wtb = (const char*)WhT + (size_t)b*32*16384;
    const int laneoff = wr*8192 + lane*16;

    {   // preload quarter's supertile 0 into buf 0
        const char* src = Wtb + (size_t)(kh*8)*16384 + laneoff;
        unsigned short* dst = &Bs[0][kh][wr*4096];
        #pragma unroll
        for (int c = 0; c < 8; ++c)
            __builtin_amdgcn_global_load_lds((gptr_t)(src + c*1024),
                                             (lptr_t)(dst + c*512), 16, 0, 0);
    }

    int buf = 0;
    for (int it = 0; it < 8; ++it){
        __syncthreads();
        if (it + 1 < 8){
            const char* src = Wtb + (size_t)(kh*8 + it + 1)*16384 + laneoff;
            unsigned short* dst = &Bs[buf^1][kh][wr*4096];
            #pragma unroll
            for (int c = 0; c < 8; ++c)
                __builtin_amdgcn_global_load_lds((gptr_t)(src + c*1024),
                                                 (lptr_t)(dst + c*512), 16, 0, 0);
        }
        const char* tile = (const char*)&Bs[buf][kh][0];
        #pragma unroll
        for (int s = 0; s < 4; ++s){
            short8 bfr[4];
            #pragma unroll
            for (int nt = 0; nt < 4; ++nt)
                bfr[nt] = *(const short8*)(tile + ((s*4 + nt)*64 + lane)*16);

            const int jb = kh*512 + it*64 + s*16 + l5*8;
            float av[8], bv[8];
            *(float4*)&av[0] = *(const float4*)&Ab[jb];
            *(float4*)&av[4] = *(const float4*)&Ab[jb+4];
            *(float4*)&bv[0] = *(const float4*)&Zb[jb];
            *(float4*)&bv[4] = *(const float4*)&Zb[jb+4];
            short8 afa;
            #pragma unroll
            for (int e = 0; e < 8; ++e)
                afa[e] = (short)bfbits(__builtin_amdgcn_exp2f(
                             fmaxf(s1a + av[e], as1a + bv[e])));
            #pragma unroll
            for (int nt = 0; nt < 4; ++nt)
                acc[nt] = __builtin_amdgcn_mfma_f32_32x32x16_bf16(afa, bfr[nt], acc[nt], 0,0,0);
        }
        buf ^= 1;
    }

    // combine 4 j-quarters through LDS (reuse Bs), ELU, store.
    __syncthreads();
    float* comb = (float*)&Bs[0][0][0];    // 4 x 32x132 f32 = 67.6 KB
    if (kh < 2){
        float* cb = comb + (size_t)(kh*2 + wr)*(32*132);
        #pragma unroll
        for (int nt = 0; nt < 4; ++nt)
            #pragma unroll
            for (int r = 0; r < 16; ++r){
                const int row = (r&3) + 8*(r>>2) + 4*l5;
                cb[row*132 + nt*32 + il] = acc[nt][r];
            }
    }
    __syncthreads();
    if (kh >= 2){
        float* cb = comb + (size_t)((kh-2)*2 + wr)*(32*132);
        #pragma unroll
        for (int nt = 0; nt < 4; ++nt)
            #pragma unroll
            for (int r = 0; r < 16; ++r){
                const int row = (r&3) + 8*(r>>2) + 4*l5;
                cb[row*132 + nt*32 + il] += acc[nt][r];
            }
    }
    __syncthreads();
    {   // all 512 threads: thread = (rgrp: 4 rows) x (c4: 4 cols), coalesced f32x4
        const int rgrp = t >> 5, c4 = (t & 31)*4;
        #pragma unroll
        for (int rr = 0; rr < 4; ++rr){
            const int row = rgrp*4 + rr;
            const int wrr = row >> 5, rin = row & 31;
            const float* r0 = comb + (size_t)(wrr)*(32*132)       + rin*132 + c4;
            const float* r1 = comb + (size_t)(2 + wrr)*(32*132)   + rin*132 + c4;
            float4 v0 = *(const float4*)r0, v1 = *(const float4*)r1;
            float o[4];
            #pragma unroll
            for (int e = 0; e < 4; ++e){
                const float x = ((const float*)&v0)[e] + ((const float*)&v1)[e];
                o[e] = x > 0.f ? x : expm1f(x);
            }
            *(float4*)&out[((size_t)(b*Nn + ibase + row))*FOUT + c4] = *(float4*)o;
        }
    }
}

extern "C" void kernel_launch(void* const* d_in, const int* in_sizes, int n_in,
                              void* d_out, int out_size, void* d_ws, size_t ws_size,
                              hipStream_t stream) {
    (void)in_sizes; (void)n_in; (void)out_size; (void)ws_size;
    const float* h = (const float*)d_in[0];
    const float* W = (const float*)d_in[1];
    const float* a = (const float*)d_in[2];
    float* out = (float*)d_out;

    float* ws    = (float*)d_ws;
    float* s1    = ws;                    // 16384 f32
    float* s2    = s1 + Bb*Nn;            // 16384 f32
    float* Aarr  = s2 + Bb*Nn;            // 16384 f32
    float* Barr  = Aarr + Bb*Nn;          // 16384 f32
    __hip_bfloat16* WhT = (__hip_bfloat16*)(Barr + Bb*Nn);  // 4 MB supertiles

    k_wh  <<<dim3(Bb*Nn/32),  dim3(256), 0, stream>>>(h, W, a, s1, s2, WhT);
    k_z   <<<dim3(Bb*64),     dim3(256), 0, stream>>>(s1, s2, Aarr, Barr);
    k_pv  <<<dim3(Bb*Nn/64),  dim3(512), 0, stream>>>(s1, Aarr, Barr, WhT, out);
}